// Round 1
// baseline (6746.702 us; speedup 1.0000x reference)
//
#include <hip/hip_runtime.h>
#include <math.h>

#define BB 4
#define CC 512
#define MM 512
#define HH 8
#define KDIM 64
#define VDIM 64
#define FF 2048
#define LLAYERS 6
#define TT 32000
#define NROWS (BB*CC)   // 2048
#define LN_EPS 1e-5f

// ---------------------------------------------------------------------------
// Generic 128x128 fp32 tiled GEMM, BK=16, 256 threads, 8x8 microtile.
// MODE_B: 0 = plain row-major B[k*ldb+n]
//         1 = transposed   B[n*ldb+k]   (for wf: logits = x @ wf^T)
//         2 = head-blocked B  (qkv weights (H,M,K): elem(k_gemm=m, n=h*64+kk))
// ---------------------------------------------------------------------------
template<int MODE_B, bool BIAS, bool RELU, bool RESID>
__device__ void gemm_body(const float* __restrict__ A, int lda,
                          const float* __restrict__ B, int ldb,
                          float* __restrict__ C, int ldc, int Kd,
                          const float* __restrict__ bias,
                          const float* __restrict__ resid,
                          int row0, int col0)
{
    __shared__ float As[16][132];   // +4 pad keeps float4 alignment, breaks stride conflicts
    __shared__ float Bs[16][132];
    const int tid = threadIdx.x;
    const int tx = tid & 15, ty = tid >> 4;
    float acc[8][8];
#pragma unroll
    for (int i = 0; i < 8; ++i)
#pragma unroll
        for (int j = 0; j < 8; ++j) acc[i][j] = 0.f;

    const int am = tid >> 1, ak0 = (tid & 1) << 3;
    const float* aptr = A + (size_t)(row0 + am) * lda + ak0;

    for (int kb = 0; kb < Kd; kb += 16) {
        // ---- stage A tile (128m x 16k), store transposed As[k][m]
        {
            float4 a0 = *(const float4*)(aptr);
            float4 a1 = *(const float4*)(aptr + 4);
            As[ak0 + 0][am] = a0.x; As[ak0 + 1][am] = a0.y;
            As[ak0 + 2][am] = a0.z; As[ak0 + 3][am] = a0.w;
            As[ak0 + 4][am] = a1.x; As[ak0 + 5][am] = a1.y;
            As[ak0 + 6][am] = a1.z; As[ak0 + 7][am] = a1.w;
            aptr += 16;
        }
        // ---- stage B tile (16k x 128n) as Bs[k][n]
        if (MODE_B == 0) {
            const int k = tid >> 4, n8 = (tid & 15) << 3;
            const float* bp = B + (size_t)(kb + k) * ldb + col0 + n8;
            *(float4*)&Bs[k][n8]     = *(const float4*)bp;
            *(float4*)&Bs[k][n8 + 4] = *(const float4*)(bp + 4);
        } else if (MODE_B == 1) {
            const int n = tid >> 1, k0 = (tid & 1) << 3;
            const float* bp = B + (size_t)(col0 + n) * ldb + kb + k0;
            float4 b0 = *(const float4*)bp;
            float4 b1 = *(const float4*)(bp + 4);
            Bs[k0 + 0][n] = b0.x; Bs[k0 + 1][n] = b0.y;
            Bs[k0 + 2][n] = b0.z; Bs[k0 + 3][n] = b0.w;
            Bs[k0 + 4][n] = b1.x; Bs[k0 + 5][n] = b1.y;
            Bs[k0 + 6][n] = b1.z; Bs[k0 + 7][n] = b1.w;
        } else {
            const int k = tid >> 4, n8 = (tid & 15) << 3;
            const int n = col0 + n8;
            const float* bp = B + (size_t)(n >> 6) * (MM * KDIM)
                                + (size_t)(kb + k) * KDIM + (n & 63);
            *(float4*)&Bs[k][n8]     = *(const float4*)bp;
            *(float4*)&Bs[k][n8 + 4] = *(const float4*)(bp + 4);
        }
        __syncthreads();
#pragma unroll
        for (int k = 0; k < 16; ++k) {
            float4 a0 = *(const float4*)&As[k][8 * ty];
            float4 a1 = *(const float4*)&As[k][8 * ty + 4];
            float4 b0 = *(const float4*)&Bs[k][8 * tx];
            float4 b1 = *(const float4*)&Bs[k][8 * tx + 4];
            float av[8] = {a0.x, a0.y, a0.z, a0.w, a1.x, a1.y, a1.z, a1.w};
            float bv[8] = {b0.x, b0.y, b0.z, b0.w, b1.x, b1.y, b1.z, b1.w};
#pragma unroll
            for (int i = 0; i < 8; ++i)
#pragma unroll
                for (int j = 0; j < 8; ++j)
                    acc[i][j] = fmaf(av[i], bv[j], acc[i][j]);
        }
        __syncthreads();
    }
    // ---- epilogue
#pragma unroll
    for (int i = 0; i < 8; ++i) {
        const int r = row0 + 8 * ty + i;
        float* crow = C + (size_t)r * ldc + col0 + 8 * tx;
        const float* rrow = RESID ? (resid + (size_t)r * ldc + col0 + 8 * tx) : (const float*)0;
#pragma unroll
        for (int jq = 0; jq < 2; ++jq) {
            float vv[4];
#pragma unroll
            for (int j = 0; j < 4; ++j) {
                float t = acc[i][4 * jq + j];
                if (BIAS)  t += bias[col0 + 8 * tx + 4 * jq + j];
                if (RESID) t += rrow[4 * jq + j];
                if (RELU)  t = fmaxf(t, 0.f);
                vv[j] = t;
            }
            float4 v = make_float4(vv[0], vv[1], vv[2], vv[3]);
            *(float4*)(crow + 4 * jq) = v;
        }
    }
}

template<bool BIAS, bool RELU, bool RESID>
__global__ __launch_bounds__(256) void gemm_plain(const float* __restrict__ A, int lda,
                                                  const float* __restrict__ B, int ldb,
                                                  float* __restrict__ C, int ldc, int Kd,
                                                  const float* __restrict__ bias,
                                                  const float* __restrict__ resid)
{
    gemm_body<0, BIAS, RELU, RESID>(A, lda, B, ldb, C, ldc, Kd, bias, resid,
                                    blockIdx.x * 128, blockIdx.y * 128);
}

__global__ __launch_bounds__(256) void gemm_transb(const float* __restrict__ A, int lda,
                                                   const float* __restrict__ B, int ldb,
                                                   float* __restrict__ C, int ldc, int Kd,
                                                   const float* __restrict__ bias)
{
    gemm_body<1, true, false, false>(A, lda, B, ldb, C, ldc, Kd, bias, (const float*)0,
                                     blockIdx.x * 128, blockIdx.y * 128);
}

// z: 0 -> Q (A = xq), 1 -> K (A = xkv), 2 -> V (A = xkv). Output layout (row, h*64+k).
__global__ __launch_bounds__(256) void qkv_ker(const float* __restrict__ xq,
                                               const float* __restrict__ xkv,
                                               const float* __restrict__ Wq,
                                               const float* __restrict__ Wk,
                                               const float* __restrict__ Wv,
                                               float* __restrict__ Qo,
                                               float* __restrict__ Ko,
                                               float* __restrict__ Vo)
{
    const int z = blockIdx.z;
    const float* A = (z == 0) ? xq : xkv;
    const float* B = (z == 0) ? Wq : (z == 1) ? Wk : Wv;
    float* C = (z == 0) ? Qo : (z == 1) ? Ko : Vo;
    gemm_body<2, false, false, false>(A, MM, B, 0, C, MM, MM, (const float*)0, (const float*)0,
                                      blockIdx.x * 128, blockIdx.y * 128);
}

// ---------------------------------------------------------------------------
// Fused attention: per block = (16 queries, head h, batch b).
// S = Q K^T (+mask)*0.125 -> softmax over keys -> out = att @ V.
// Q/K/V layout: (b*C + c) * 512 + h*64 + k.  Output pre same layout.
// ---------------------------------------------------------------------------
template<bool MASKED>
__global__ __launch_bounds__(256) void attn_ker(const float* __restrict__ Q,
                                                const float* __restrict__ Kb,
                                                const float* __restrict__ Vb,
                                                float* __restrict__ P)
{
    __shared__ float Sf[16][516];        // full score rows (16 x 512)
    __shared__ float QT[64][20];         // Q transposed [k][d]
    __shared__ float KVu[4352];          // union: KT[32][132] (16.5KB) / Vs[64][68] (17KB)
    float (*KT)[132] = (float(*)[132])KVu;
    float (*Vs)[68]  = (float(*)[68])KVu;

    const int b = blockIdx.z, h = blockIdx.y, d0 = blockIdx.x * 16;
    const int tid = threadIdx.x;

    // load Q tile (16 d x 64 k) -> QT[k][d]
    {
        const int d = tid >> 4, k0 = (tid & 15) << 2;
        const float4 qv = *(const float4*)(Q + ((size_t)(b * CC + d0 + d) * MM) + h * KDIM + k0);
        QT[k0 + 0][d] = qv.x; QT[k0 + 1][d] = qv.y;
        QT[k0 + 2][d] = qv.z; QT[k0 + 3][d] = qv.w;
    }

    // phase 1: scores, c-chunks of 128, two k-passes of 32
    const int ty = tid >> 5;     // 0..7 -> d = 2*ty + i
    const int tx = tid & 31;     // c4 = 4*tx
    for (int cb = 0; cb < CC; cb += 128) {
        float s[2][4] = {{0.f,0.f,0.f,0.f},{0.f,0.f,0.f,0.f}};
        for (int kh = 0; kh < 64; kh += 32) {
            __syncthreads();   // protect KT reuse (and QT stores on first pass)
            {   // load K chunk: 128 c x 32 k -> KT[k][c]
                const int cbase = tid >> 3;            // 0..31
                const int k0 = (tid & 7) << 2;         // 0..28
#pragma unroll
                for (int r = 0; r < 4; ++r) {
                    const int ci = cbase + 32 * r;
                    const float4 kv = *(const float4*)(Kb + ((size_t)(b * CC + cb + ci) * MM)
                                                        + h * KDIM + kh + k0);
                    KT[k0 + 0][ci] = kv.x; KT[k0 + 1][ci] = kv.y;
                    KT[k0 + 2][ci] = kv.z; KT[k0 + 3][ci] = kv.w;
                }
            }
            __syncthreads();
#pragma unroll
            for (int k = 0; k < 32; ++k) {
                const float q0 = QT[kh + k][2 * ty];
                const float q1 = QT[kh + k][2 * ty + 1];
                const float4 kv = *(const float4*)&KT[k][4 * tx];
                s[0][0] = fmaf(q0, kv.x, s[0][0]); s[0][1] = fmaf(q0, kv.y, s[0][1]);
                s[0][2] = fmaf(q0, kv.z, s[0][2]); s[0][3] = fmaf(q0, kv.w, s[0][3]);
                s[1][0] = fmaf(q1, kv.x, s[1][0]); s[1][1] = fmaf(q1, kv.y, s[1][1]);
                s[1][2] = fmaf(q1, kv.z, s[1][2]); s[1][3] = fmaf(q1, kv.w, s[1][3]);
            }
        }
        const int dg0 = d0 + 2 * ty;
#pragma unroll
        for (int i = 0; i < 2; ++i) {
            const int dg = dg0 + i;
#pragma unroll
            for (int j = 0; j < 4; ++j) {
                const int cg = cb + 4 * tx + j;
                float v = s[i][j];
                if (MASKED && dg >= cg) v -= 100.f;   // mask added BEFORE scale
                Sf[2 * ty + i][cb + 4 * tx + j] = v * 0.125f;
            }
        }
    }
    __syncthreads();
    // phase 2: softmax over keys (row of 512), 16 lanes per row
    {
        const int d = tid >> 4, lane = tid & 15;
        float mx = -3.4e38f;
        for (int i = 0; i < 32; ++i) mx = fmaxf(mx, Sf[d][lane + 16 * i]);
#pragma unroll
        for (int o = 8; o; o >>= 1) mx = fmaxf(mx, __shfl_xor(mx, o, 16));
        float sum = 0.f;
        for (int i = 0; i < 32; ++i) {
            const float e = expf(Sf[d][lane + 16 * i] - mx);
            Sf[d][lane + 16 * i] = e;
            sum += e;
        }
#pragma unroll
        for (int o = 8; o; o >>= 1) sum += __shfl_xor(sum, o, 16);
        const float inv = 1.f / sum;
        for (int i = 0; i < 32; ++i) Sf[d][lane + 16 * i] *= inv;
    }
    // phase 3: out = att @ V, thread = (d, 4 v)
    float o0 = 0.f, o1 = 0.f, o2 = 0.f, o3 = 0.f;
    const int d = tid >> 4, v4 = (tid & 15) << 2;
    for (int cb = 0; cb < CC; cb += 64) {
        __syncthreads();   // also orders softmax writes before first AV read
        {   // load V chunk: 64 c x 64 v -> Vs[c][v]
            const int cbase = tid >> 3;            // 0..31
            const int k0 = (tid & 7) << 3;         // 0,8,...,56
#pragma unroll
            for (int r = 0; r < 2; ++r) {
                const int c = cbase + 32 * r;
                const float* src = Vb + ((size_t)(b * CC + cb + c) * MM) + h * KDIM + k0;
                *(float4*)&Vs[c][k0]     = *(const float4*)src;
                *(float4*)&Vs[c][k0 + 4] = *(const float4*)(src + 4);
            }
        }
        __syncthreads();
#pragma unroll
        for (int c = 0; c < 64; ++c) {
            const float a = Sf[d][cb + c];
            const float4 vv = *(const float4*)&Vs[c][v4];
            o0 = fmaf(a, vv.x, o0); o1 = fmaf(a, vv.y, o1);
            o2 = fmaf(a, vv.z, o2); o3 = fmaf(a, vv.w, o3);
        }
    }
    *(float4*)(P + ((size_t)(b * CC + d0 + d) * MM) + h * VDIM + v4) = make_float4(o0, o1, o2, o3);
}

// ---------------------------------------------------------------------------
// LayerNorm over last dim (512). One block per row, 256 threads x 2 elems.
// ---------------------------------------------------------------------------
__global__ __launch_bounds__(256) void ln_ker(const float* __restrict__ Y,
                                              float* __restrict__ X,
                                              const float* __restrict__ g,
                                              const float* __restrict__ bta)
{
    const int row = blockIdx.x;
    const float* y = Y + (size_t)row * MM;
    const int tid = threadIdx.x;
    const float v0 = y[tid], v1 = y[tid + 256];
    float s = v0 + v1;
#pragma unroll
    for (int o = 32; o; o >>= 1) s += __shfl_xor(s, o, 64);
    __shared__ float red[4];
    if ((tid & 63) == 0) red[tid >> 6] = s;
    __syncthreads();
    const float mean = (red[0] + red[1] + red[2] + red[3]) * (1.f / 512.f);
    const float d0 = v0 - mean, d1 = v1 - mean;
    float p = d0 * d0 + d1 * d1;
#pragma unroll
    for (int o = 32; o; o >>= 1) p += __shfl_xor(p, o, 64);
    __syncthreads();
    if ((tid & 63) == 0) red[tid >> 6] = p;
    __syncthreads();
    const float var = (red[0] + red[1] + red[2] + red[3]) * (1.f / 512.f);
    const float rs = 1.0f / sqrtf(var + LN_EPS);
    X[(size_t)row * MM + tid]       = d0 * rs * g[tid] + bta[tid];
    X[(size_t)row * MM + tid + 256] = d1 * rs * g[tid + 256] + bta[tid + 256];
}

// ---------------------------------------------------------------------------
// Embedding gather + sinusoidal positional encoding (double for f64-ref match).
// ---------------------------------------------------------------------------
__global__ __launch_bounds__(256) void embed_ker(const int* __restrict__ idx,
                                                 const float* __restrict__ emb,
                                                 float* __restrict__ X)
{
    const int row = blockIdx.x;
    const int c = row & (CC - 1);
    const int t = idx[row];
    for (int m = threadIdx.x; m < MM; m += 256) {
        const double dn = pow(10000.0, (double)m * (1.0 / 511.0));
        const double arg = (double)c / dn;
        const double pv = (m & 1) ? cos(arg) : sin(arg);
        X[(size_t)row * MM + m] = emb[(size_t)t * MM + m] + (float)pv;
    }
}

// ---------------------------------------------------------------------------
// Final softmax: row max + 1/sumexp (pass 1), in-place normalize (pass 2).
// ---------------------------------------------------------------------------
__global__ __launch_bounds__(256) void rowstat_ker(const float* __restrict__ Z,
                                                   float* __restrict__ stats)
{
    const int row = blockIdx.x;
    const float* z = Z + (size_t)row * TT;
    const int tid = threadIdx.x;
    float mx = -3.4e38f;
    for (int i = tid; i < TT; i += 256) mx = fmaxf(mx, z[i]);
#pragma unroll
    for (int o = 32; o; o >>= 1) mx = fmaxf(mx, __shfl_xor(mx, o, 64));
    __shared__ float red[4];
    if ((tid & 63) == 0) red[tid >> 6] = mx;
    __syncthreads();
    mx = fmaxf(fmaxf(red[0], red[1]), fmaxf(red[2], red[3]));
    float sm = 0.f;
    for (int i = tid; i < TT; i += 256) sm += expf(z[i] - mx);
#pragma unroll
    for (int o = 32; o; o >>= 1) sm += __shfl_xor(sm, o, 64);
    __syncthreads();
    if ((tid & 63) == 0) red[tid >> 6] = sm;
    __syncthreads();
    sm = red[0] + red[1] + red[2] + red[3];
    if (tid == 0) { stats[2 * row] = mx; stats[2 * row + 1] = 1.f / sm; }
}

__global__ __launch_bounds__(256) void finalnorm_ker(float* __restrict__ Z,
                                                     const float* __restrict__ stats)
{
    const unsigned i4 = blockIdx.x * 256u + threadIdx.x;   // one float4 each; grid exact
    const unsigned idx = i4 * 4u;
    const unsigned row = idx / (unsigned)TT;
    const float mx = stats[2 * row], inv = stats[2 * row + 1];
    float4 v = ((float4*)Z)[i4];
    v.x = expf(v.x - mx) * inv;
    v.y = expf(v.y - mx) * inv;
    v.z = expf(v.z - mx) * inv;
    v.w = expf(v.w - mx) * inv;
    ((float4*)Z)[i4] = v;
}

// ---------------------------------------------------------------------------
extern "C" void kernel_launch(void* const* d_in, const int* in_sizes, int n_in,
                              void* d_out, int out_size, void* d_ws, size_t ws_size,
                              hipStream_t stream)
{
    const float* enc = (const float*)d_in[0];
    const int*   dec = (const int*)d_in[1];
    const float* emb = (const float*)d_in[2];
    const float* wq  = (const float*)d_in[3];
    const float* wk  = (const float*)d_in[4];
    const float* wv  = (const float*)d_in[5];
    const float* wo  = (const float*)d_in[6];
    const float* w1  = (const float*)d_in[7];
    const float* b1  = (const float*)d_in[8];
    const float* w2  = (const float*)d_in[9];
    const float* b2  = (const float*)d_in[10];
    const float* lng = (const float*)d_in[11];
    const float* lnb = (const float*)d_in[12];
    const float* wf  = (const float*)d_in[13];
    const float* bf  = (const float*)d_in[14];
    float* out = (float*)d_out;

    float* W   = (float*)d_ws;
    float* x   = W;                    // 1M floats
    float* y   = W + 1 * 1048576;      // 1M
    float* qb  = W + 2 * 1048576;      // 1M
    float* kb  = W + 3 * 1048576;      // 1M
    float* vb  = W + 4 * 1048576;      // 1M
    float* pre = W + 5 * 1048576;      // 1M
    float* hid = W + 2 * 1048576;      // aliases qb..pre (dead during FFN), 4M
    float* stats = W + 6 * 1048576;    // 4096

    embed_ker<<<dim3(NROWS), 256, 0, stream>>>(dec, emb, x);

    for (int l = 0; l < LLAYERS; ++l) {
        for (int s = 0; s < 2; ++s) {
            const size_t awoff = (size_t)(l * 2 + s) * HH * MM * KDIM;
            const float* kvsrc = (s == 0) ? x : enc;
            qkv_ker<<<dim3(16, 4, 3), 256, 0, stream>>>(x, kvsrc,
                wq + awoff, wk + awoff, wv + awoff, qb, kb, vb);
            if (s == 0)
                attn_ker<true><<<dim3(32, 8, 4), 256, 0, stream>>>(qb, kb, vb, pre);
            else
                attn_ker<false><<<dim3(32, 8, 4), 256, 0, stream>>>(qb, kb, vb, pre);
            gemm_plain<false, false, true><<<dim3(16, 4), 256, 0, stream>>>(
                pre, MM, wo + awoff, MM, y, MM, MM, (const float*)0, x);
            ln_ker<<<dim3(NROWS), 256, 0, stream>>>(y, x,
                lng + (size_t)(l * 3 + s) * MM, lnb + (size_t)(l * 3 + s) * MM);
        }
        // FFN
        gemm_plain<true, true, false><<<dim3(16, 16), 256, 0, stream>>>(
            x, MM, w1 + (size_t)l * MM * FF, FF, hid, FF, MM, b1 + (size_t)l * FF, (const float*)0);
        gemm_plain<true, false, true><<<dim3(16, 4), 256, 0, stream>>>(
            hid, FF, w2 + (size_t)l * FF * MM, MM, y, MM, FF, b2 + (size_t)l * MM, x);
        ln_ker<<<dim3(NROWS), 256, 0, stream>>>(y, x,
            lng + (size_t)(l * 3 + 2) * MM, lnb + (size_t)(l * 3 + 2) * MM);
    }

    // Final projection: logits -> d_out, then softmax over T in place.
    gemm_transb<<<dim3(16, 250), 256, 0, stream>>>(x, MM, wf, MM, out, TT, MM, bf);
    rowstat_ker<<<dim3(NROWS), 256, 0, stream>>>(out, stats);
    finalnorm_ker<<<dim3(64000), 256, 0, stream>>>(out, stats);
}

// Round 2
// 3378.362 us; speedup vs baseline: 1.9970x; 1.9970x over previous
//
#include <hip/hip_runtime.h>
#include <math.h>

#define BB 4
#define CC 512
#define MM 512
#define HH 8
#define KDIM 64
#define VDIM 64
#define FF 2048
#define LLAYERS 6
#define TT 32000
#define NROWS (BB*CC)   // 2048
#define LN_EPS 1e-5f

typedef short bf16x8 __attribute__((ext_vector_type(8)));
typedef float f32x4 __attribute__((ext_vector_type(4)));

// ---- bf16 split helpers ----------------------------------------------------
__device__ __forceinline__ unsigned short f2bf(float f) {
    unsigned u = __float_as_uint(f);
    return (unsigned short)((u + 0x7FFFu + ((u >> 16) & 1u)) >> 16);   // RNE
}
__device__ __forceinline__ float bf2f(unsigned short h) {
    return __uint_as_float(((unsigned)h) << 16);
}
__device__ __forceinline__ void split8(const float* v, uint4& H, uint4& L) {
    unsigned short h[8], l[8];
#pragma unroll
    for (int i = 0; i < 8; ++i) {
        h[i] = f2bf(v[i]);
        l[i] = f2bf(v[i] - bf2f(h[i]));
    }
    H.x = h[0] | ((unsigned)h[1] << 16); H.y = h[2] | ((unsigned)h[3] << 16);
    H.z = h[4] | ((unsigned)h[5] << 16); H.w = h[6] | ((unsigned)h[7] << 16);
    L.x = l[0] | ((unsigned)l[1] << 16); L.y = l[2] | ((unsigned)l[3] << 16);
    L.z = l[4] | ((unsigned)l[5] << 16); L.w = l[6] | ((unsigned)l[7] << 16);
}

// BFI format: per row of K elems: K/8 chunks of 16 ushorts = [hi0..hi7][lo0..lo7].
// Row stride = K*2 ushorts. A k8-aligned 16B read gives one MFMA half-frag.

// ---------------------------------------------------------------------------
// Split-bf16 MFMA GEMM. 128x128 tile, BK=32, 256 thr = 4 waves (each 64x64).
// MODE_B: 0 = B pre-converted BFI; 1 = B fp32 [n][k] k-contiguous (convert in staging)
// ---------------------------------------------------------------------------
template<int MODE_B, bool BIAS, bool RELU, bool RESID, bool OUTBF>
__device__ void mfma_body(const unsigned short* __restrict__ Abf,
                          const void* __restrict__ Bsrc,
                          float* __restrict__ C, unsigned short* __restrict__ Cbf,
                          int ldc, int Kd,
                          const float* __restrict__ bias,
                          const float* __restrict__ resid,
                          int row0, int col0)
{
    __shared__ unsigned short As[128 * 72];   // rows of 4 chunks (64) + 8 pad = 144 B
    __shared__ unsigned short Bs[128 * 72];
    const int tid = threadIdx.x;

    f32x4 acc[4][4];
    const f32x4 z4 = {0.f, 0.f, 0.f, 0.f};
#pragma unroll
    for (int i = 0; i < 4; ++i)
#pragma unroll
        for (int j = 0; j < 4; ++j) acc[i][j] = z4;

    const int lid = tid & 63, wid = tid >> 6;
    const int mw = (wid & 1) << 6, nw = (wid >> 1) << 6;
    const int fr = lid & 15, fq = lid >> 4;

    // staging slots: slot s in {tid, tid+256}: m = s>>2, q = s&3
    const int m1 = tid >> 2, q1 = tid & 3;
    const unsigned short* a1 = Abf + (size_t)(row0 + m1) * (Kd * 2) + q1 * 16;
    const unsigned short* a2 = a1 + (size_t)64 * (Kd * 2);
    const unsigned short* bb1 = 0; const unsigned short* bb2 = 0;
    const float* bf1 = 0; const float* bf2p = 0;
    if (MODE_B == 0) {
        bb1 = (const unsigned short*)Bsrc + (size_t)(col0 + m1) * (Kd * 2) + q1 * 16;
        bb2 = bb1 + (size_t)64 * (Kd * 2);
    } else {
        bf1 = (const float*)Bsrc + (size_t)(col0 + m1) * Kd + q1 * 8;
        bf2p = bf1 + (size_t)64 * Kd;
    }

    for (int kb = 0; kb < Kd; kb += 32) {
        {   // stage A (BFI copy)
            uint4* d1 = (uint4*)&As[m1 * 72 + q1 * 16];
            const uint4* s1 = (const uint4*)a1;
            d1[0] = s1[0]; d1[1] = s1[1];
            uint4* d2 = (uint4*)&As[(m1 + 64) * 72 + q1 * 16];
            const uint4* s2 = (const uint4*)a2;
            d2[0] = s2[0]; d2[1] = s2[1];
        }
        if (MODE_B == 0) {
            uint4* d1 = (uint4*)&Bs[m1 * 72 + q1 * 16];
            const uint4* s1 = (const uint4*)bb1;
            d1[0] = s1[0]; d1[1] = s1[1];
            uint4* d2 = (uint4*)&Bs[(m1 + 64) * 72 + q1 * 16];
            const uint4* s2 = (const uint4*)bb2;
            d2[0] = s2[0]; d2[1] = s2[1];
            bb1 += 64; bb2 += 64;
        } else {
            float v[8];
            *(float4*)&v[0] = *(const float4*)bf1;
            *(float4*)&v[4] = *(const float4*)(bf1 + 4);
            uint4 H, L; split8(v, H, L);
            uint4* d1 = (uint4*)&Bs[m1 * 72 + q1 * 16];
            d1[0] = H; d1[1] = L;
            *(float4*)&v[0] = *(const float4*)bf2p;
            *(float4*)&v[4] = *(const float4*)(bf2p + 4);
            split8(v, H, L);
            uint4* d2 = (uint4*)&Bs[(m1 + 64) * 72 + q1 * 16];
            d2[0] = H; d2[1] = L;
            bf1 += 32; bf2p += 32;
        }
        a1 += 64; a2 += 64;
        __syncthreads();

        bf16x8 ah[4], al[4];
#pragma unroll
        for (int i = 0; i < 4; ++i) {
            const unsigned short* p = &As[(mw + 16 * i + fr) * 72 + fq * 16];
            ah[i] = *(const bf16x8*)p;
            al[i] = *(const bf16x8*)(p + 8);
        }
#pragma unroll
        for (int j = 0; j < 4; ++j) {
            const unsigned short* p = &Bs[(nw + 16 * j + fr) * 72 + fq * 16];
            bf16x8 bh = *(const bf16x8*)p;
            bf16x8 bl = *(const bf16x8*)(p + 8);
#pragma unroll
            for (int i = 0; i < 4; ++i) {
                acc[i][j] = __builtin_amdgcn_mfma_f32_16x16x32_bf16(ah[i], bh, acc[i][j], 0, 0, 0);
                acc[i][j] = __builtin_amdgcn_mfma_f32_16x16x32_bf16(al[i], bh, acc[i][j], 0, 0, 0);
                acc[i][j] = __builtin_amdgcn_mfma_f32_16x16x32_bf16(ah[i], bl, acc[i][j], 0, 0, 0);
            }
        }
        __syncthreads();
    }

    // epilogue: C/D layout: row = fq*4 + r, col = fr  [m89/m91-verified]
#pragma unroll
    for (int i = 0; i < 4; ++i) {
        const int rbase = row0 + mw + 16 * i + fq * 4;
#pragma unroll
        for (int j = 0; j < 4; ++j) {
            const int col = col0 + nw + 16 * j + fr;
            const float bv = BIAS ? bias[col] : 0.f;
#pragma unroll
            for (int r = 0; r < 4; ++r) {
                const int row = rbase + r;
                float v = acc[i][j][r] + bv;
                if (RESID) v += resid[(size_t)row * ldc + col];
                if (RELU)  v = fmaxf(v, 0.f);
                if (OUTBF) {
                    const unsigned short h = f2bf(v);
                    const unsigned short lo = f2bf(v - bf2f(h));
                    const size_t o = (size_t)row * (ldc * 2) + (size_t)(col >> 3) * 16 + (col & 7);
                    Cbf[o] = h; Cbf[o + 8] = lo;
                } else {
                    C[(size_t)row * ldc + col] = v;
                }
            }
        }
    }
}

// wrappers
__global__ __launch_bounds__(256) void g_qkv(const unsigned short* __restrict__ xbf,
                                             const unsigned short* __restrict__ kvbf,
                                             const unsigned short* __restrict__ Wc,
                                             float* __restrict__ Q, float* __restrict__ K,
                                             float* __restrict__ V)
{
    const int z = blockIdx.z;
    const unsigned short* A = (z == 0) ? xbf : kvbf;
    const unsigned short* B = Wc + (size_t)z * 524288;
    float* C = (z == 0) ? Q : (z == 1) ? K : V;
    mfma_body<0, false, false, false, false>(A, B, C, 0, MM, MM, 0, 0,
                                             blockIdx.x * 128, blockIdx.y * 128);
}

__global__ __launch_bounds__(256) void g_wo(const unsigned short* __restrict__ prebf,
                                            const unsigned short* __restrict__ Wc,
                                            float* __restrict__ Y, const float* __restrict__ X)
{
    mfma_body<0, false, false, true, false>(prebf, Wc, Y, 0, MM, MM, 0, X,
                                            blockIdx.x * 128, blockIdx.y * 128);
}

__global__ __launch_bounds__(256) void g_ffn1(const unsigned short* __restrict__ xbf,
                                              const unsigned short* __restrict__ Wc,
                                              unsigned short* __restrict__ hidbf,
                                              const float* __restrict__ bias)
{
    mfma_body<0, true, true, false, true>(xbf, Wc, 0, hidbf, FF, MM, bias, 0,
                                          blockIdx.x * 128, blockIdx.y * 128);
}

__global__ __launch_bounds__(256) void g_ffn2(const unsigned short* __restrict__ hidbf,
                                              const unsigned short* __restrict__ Wc,
                                              float* __restrict__ Y, const float* __restrict__ X,
                                              const float* __restrict__ bias)
{
    mfma_body<0, true, false, true, false>(hidbf, Wc, Y, 0, MM, FF, bias, X,
                                           blockIdx.x * 128, blockIdx.y * 128);
}

__global__ __launch_bounds__(256) void g_transb(const unsigned short* __restrict__ xbf,
                                                const float* __restrict__ wf,
                                                float* __restrict__ out,
                                                const float* __restrict__ bias)
{
    mfma_body<1, true, false, false, false>(xbf, wf, out, 0, TT, MM, bias, 0,
                                            blockIdx.x * 128, blockIdx.y * 128);
}

// ---------------------------------------------------------------------------
// Weight transpose+convert: fp32 (k-major) -> BFI [n][k]. 64x64 tiles via LDS.
// ---------------------------------------------------------------------------
__global__ __launch_bounds__(256) void conv_weights(const float* __restrict__ wq,
                                                    const float* __restrict__ wk,
                                                    const float* __restrict__ wv,
                                                    const float* __restrict__ wo,
                                                    const float* __restrict__ w1,
                                                    const float* __restrict__ w2,
                                                    unsigned short* __restrict__ Wattn,
                                                    unsigned short* __restrict__ Wffn)
{
    const int b = blockIdx.x;
    const float* src; unsigned short* dst; int rs, Kd;
    if (b < 2304) {                 // wq/wk/wv: 12 l2 x 3 mat x (8 kt x 8 nt)
        const int l2 = b / 192, rem = b % 192;
        const int mat = rem / 64, t = rem % 64;
        const int kt = t >> 3, nt = t & 7;
        const float* base = (mat == 0) ? wq : (mat == 1) ? wk : wv;
        src = base + (size_t)l2 * 262144 + (size_t)nt * 32768 + (size_t)kt * 64 * 64;
        rs = 64; Kd = 512;
        dst = Wattn + (size_t)l2 * 2097152 + (size_t)mat * 524288
                    + (size_t)(nt * 64) * 1024 + kt * 128;
    } else if (b < 3072) {          // wo: 12 x (8 kt x 8 nt)
        const int bb = b - 2304, l2 = bb / 64, t = bb % 64;
        const int kt = t >> 3, nt = t & 7;
        src = wo + (size_t)l2 * 262144 + (size_t)(kt * 64) * 512 + nt * 64;
        rs = 512; Kd = 512;
        dst = Wattn + (size_t)l2 * 2097152 + (size_t)3 * 524288
                    + (size_t)(nt * 64) * 1024 + kt * 128;
    } else if (b < 4608) {          // w1: 6 x (8 kt x 32 nt)
        const int bb = b - 3072, l = bb / 256, t = bb % 256;
        const int kt = t >> 5, nt = t & 31;
        src = w1 + (size_t)l * 1048576 + (size_t)(kt * 64) * 2048 + nt * 64;
        rs = 2048; Kd = 512;
        dst = Wffn + (size_t)l * 4194304 + (size_t)(nt * 64) * 1024 + kt * 128;
    } else {                        // w2: 6 x (32 kt x 8 nt)
        const int bb = b - 4608, l = bb / 256, t = bb % 256;
        const int kt = t >> 3, nt = t & 7;
        src = w2 + (size_t)l * 1048576 + (size_t)(kt * 64) * 512 + nt * 64;
        rs = 512; Kd = 2048;
        dst = Wffn + (size_t)l * 4194304 + 2097152 + (size_t)(nt * 64) * 4096 + kt * 128;
    }

    __shared__ float T[64][65];     // [n][k]
    const int tid = threadIdx.x;
#pragma unroll
    for (int p = 0; p < 4; ++p) {
        const int k = (tid >> 4) + 16 * p, nl = (tid & 15) * 4;
        const float4 v = *(const float4*)(src + (size_t)k * rs + nl);
        T[nl + 0][k] = v.x; T[nl + 1][k] = v.y; T[nl + 2][k] = v.z; T[nl + 3][k] = v.w;
    }
    __syncthreads();
#pragma unroll
    for (int half = 0; half < 2; ++half) {
        const int n = (tid >> 3) + 32 * half, q = tid & 7;
        float v[8];
#pragma unroll
        for (int j = 0; j < 8; ++j) v[j] = T[n][q * 8 + j];
        uint4 H, L; split8(v, H, L);
        unsigned short* d = dst + (size_t)n * (Kd * 2) + q * 16;
        *(uint4*)d = H; *(uint4*)(d + 8) = L;
    }
}

// contiguous fp32 -> BFI (row length % 8 == 0 makes this layout-agnostic)
__global__ __launch_bounds__(256) void conv_act(const float* __restrict__ src,
                                                unsigned short* __restrict__ dst)
{
    const size_t i = (size_t)blockIdx.x * 256 + threadIdx.x;   // one 8-elem chunk
    float v[8];
    *(float4*)&v[0] = *(const float4*)(src + i * 8);
    *(float4*)&v[4] = *(const float4*)(src + i * 8 + 4);
    uint4 H, L; split8(v, H, L);
    *(uint4*)(dst + i * 16) = H;
    *(uint4*)(dst + i * 16 + 8) = L;
}

// ---------------------------------------------------------------------------
// Fused attention (fp32 compute), epilogue emits BFI. One block = (16 q, h, b).
// ---------------------------------------------------------------------------
template<bool MASKED>
__global__ __launch_bounds__(256) void attn_ker(const float* __restrict__ Q,
                                                const float* __restrict__ Kb,
                                                const float* __restrict__ Vb,
                                                unsigned short* __restrict__ Pbf)
{
    __shared__ float Sf[16][516];
    __shared__ float QT[64][20];
    __shared__ float KVu[4352];
    float (*KT)[132] = (float(*)[132])KVu;
    float (*Vs)[68]  = (float(*)[68])KVu;

    const int b = blockIdx.z, h = blockIdx.y, d0 = blockIdx.x * 16;
    const int tid = threadIdx.x;

    {
        const int d = tid >> 4, k0 = (tid & 15) << 2;
        const float4 qv = *(const float4*)(Q + ((size_t)(b * CC + d0 + d) * MM) + h * KDIM + k0);
        QT[k0 + 0][d] = qv.x; QT[k0 + 1][d] = qv.y;
        QT[k0 + 2][d] = qv.z; QT[k0 + 3][d] = qv.w;
    }

    const int ty = tid >> 5, tx = tid & 31;
    for (int cb = 0; cb < CC; cb += 128) {
        float s[2][4] = {{0.f,0.f,0.f,0.f},{0.f,0.f,0.f,0.f}};
        for (int kh = 0; kh < 64; kh += 32) {
            __syncthreads();
            {
                const int cbase = tid >> 3, k0 = (tid & 7) << 2;
#pragma unroll
                for (int r = 0; r < 4; ++r) {
                    const int ci = cbase + 32 * r;
                    const float4 kv = *(const float4*)(Kb + ((size_t)(b * CC + cb + ci) * MM)
                                                        + h * KDIM + kh + k0);
                    KT[k0 + 0][ci] = kv.x; KT[k0 + 1][ci] = kv.y;
                    KT[k0 + 2][ci] = kv.z; KT[k0 + 3][ci] = kv.w;
                }
            }
            __syncthreads();
#pragma unroll
            for (int k = 0; k < 32; ++k) {
                const float q0 = QT[kh + k][2 * ty];
                const float q1 = QT[kh + k][2 * ty + 1];
                const float4 kv = *(const float4*)&KT[k][4 * tx];
                s[0][0] = fmaf(q0, kv.x, s[0][0]); s[0][1] = fmaf(q0, kv.y, s[0][1]);
                s[0][2] = fmaf(q0, kv.z, s[0][2]); s[0][3] = fmaf(q0, kv.w, s[0][3]);
                s[1][0] = fmaf(q1, kv.x, s[1][0]); s[1][1] = fmaf(q1, kv.y, s[1][1]);
                s[1][2] = fmaf(q1, kv.z, s[1][2]); s[1][3] = fmaf(q1, kv.w, s[1][3]);
            }
        }
        const int dg0 = d0 + 2 * ty;
#pragma unroll
        for (int i = 0; i < 2; ++i) {
            const int dg = dg0 + i;
#pragma unroll
            for (int j = 0; j < 4; ++j) {
                const int cg = cb + 4 * tx + j;
                float v = s[i][j];
                if (MASKED && dg >= cg) v -= 100.f;
                Sf[2 * ty + i][cb + 4 * tx + j] = v * 0.125f;
            }
        }
    }
    __syncthreads();
    {
        const int d = tid >> 4, lane = tid & 15;
        float mx = -3.4e38f;
        for (int i = 0; i < 32; ++i) mx = fmaxf(mx, Sf[d][lane + 16 * i]);
#pragma unroll
        for (int o = 8; o; o >>= 1) mx = fmaxf(mx, __shfl_xor(mx, o, 16));
        float sum = 0.f;
        for (int i = 0; i < 32; ++i) {
            const float e = expf(Sf[d][lane + 16 * i] - mx);
            Sf[d][lane + 16 * i] = e;
            sum += e;
        }
#pragma unroll
        for (int o = 8; o; o >>= 1) sum += __shfl_xor(sum, o, 16);
        const float inv = 1.f / sum;
        for (int i = 0; i < 32; ++i) Sf[d][lane + 16 * i] *= inv;
    }
    float o0 = 0.f, o1 = 0.f, o2 = 0.f, o3 = 0.f;
    const int d = tid >> 4, v4 = (tid & 15) << 2;
    for (int cb = 0; cb < CC; cb += 64) {
        __syncthreads();
        {
            const int cbase = tid >> 3, k0 = (tid & 7) << 3;
#pragma unroll
            for (int r = 0; r < 2; ++r) {
                const int c = cbase + 32 * r;
                const float* srcp = Vb + ((size_t)(b * CC + cb + c) * MM) + h * KDIM + k0;
                *(float4*)&Vs[c][k0]     = *(const float4*)srcp;
                *(float4*)&Vs[c][k0 + 4] = *(const float4*)(srcp + 4);
            }
        }
        __syncthreads();
#pragma unroll
        for (int c = 0; c < 64; ++c) {
            const float a = Sf[d][cb + c];
            const float4 vv = *(const float4*)&Vs[c][v4];
            o0 = fmaf(a, vv.x, o0); o1 = fmaf(a, vv.y, o1);
            o2 = fmaf(a, vv.z, o2); o3 = fmaf(a, vv.w, o3);
        }
    }
    // epilogue -> BFI
    {
        const int kap = h * KDIM + v4;         // global k index of o0
        const unsigned short h0 = f2bf(o0), h1 = f2bf(o1), h2 = f2bf(o2), h3 = f2bf(o3);
        const unsigned short l0 = f2bf(o0 - bf2f(h0)), l1 = f2bf(o1 - bf2f(h1));
        const unsigned short l2 = f2bf(o2 - bf2f(h2)), l3 = f2bf(o3 - bf2f(h3));
        const size_t base = (size_t)(b * CC + d0 + d) * 1024 + (size_t)(kap >> 3) * 16 + (kap & 7);
        uint2 hv, lv;
        hv.x = h0 | ((unsigned)h1 << 16); hv.y = h2 | ((unsigned)h3 << 16);
        lv.x = l0 | ((unsigned)l1 << 16); lv.y = l2 | ((unsigned)l3 << 16);
        *(uint2*)&Pbf[base] = hv;
        *(uint2*)&Pbf[base + 8] = lv;
    }
}

// ---------------------------------------------------------------------------
// LayerNorm: writes fp32 x (residual source) + BFI xbf (next GEMM's A).
// ---------------------------------------------------------------------------
__global__ __launch_bounds__(256) void ln_ker(const float* __restrict__ Y,
                                              float* __restrict__ X,
                                              unsigned short* __restrict__ Xbf,
                                              const float* __restrict__ g,
                                              const float* __restrict__ bta)
{
    const int row = blockIdx.x;
    const int tid = threadIdx.x;
    const int e0 = 2 * tid;
    const float2 v = *(const float2*)(Y + (size_t)row * MM + e0);
    float s = v.x + v.y;
#pragma unroll
    for (int o = 32; o; o >>= 1) s += __shfl_xor(s, o, 64);
    __shared__ float red[4];
    if ((tid & 63) == 0) red[tid >> 6] = s;
    __syncthreads();
    const float mean = (red[0] + red[1] + red[2] + red[3]) * (1.f / 512.f);
    const float d0 = v.x - mean, d1 = v.y - mean;
    float p = d0 * d0 + d1 * d1;
#pragma unroll
    for (int o = 32; o; o >>= 1) p += __shfl_xor(p, o, 64);
    __syncthreads();
    if ((tid & 63) == 0) red[tid >> 6] = p;
    __syncthreads();
    const float var = (red[0] + red[1] + red[2] + red[3]) * (1.f / 512.f);
    const float rsn = 1.0f / sqrtf(var + LN_EPS);
    const float2 gg = *(const float2*)(g + e0);
    const float2 bb = *(const float2*)(bta + e0);
    const float o0 = d0 * rsn * gg.x + bb.x;
    const float o1 = d1 * rsn * gg.y + bb.y;
    *(float2*)(X + (size_t)row * MM + e0) = make_float2(o0, o1);
    const unsigned short h0 = f2bf(o0), h1 = f2bf(o1);
    const unsigned short l0 = f2bf(o0 - bf2f(h0)), l1 = f2bf(o1 - bf2f(h1));
    const size_t base = (size_t)row * 1024 + (size_t)(tid >> 2) * 16 + (e0 & 7);
    *(unsigned*)&Xbf[base]     = h0 | ((unsigned)h1 << 16);
    *(unsigned*)&Xbf[base + 8] = l0 | ((unsigned)l1 << 16);
}

// ---------------------------------------------------------------------------
__global__ __launch_bounds__(256) void embed_ker(const int* __restrict__ idx,
                                                 const float* __restrict__ emb,
                                                 float* __restrict__ X,
                                                 unsigned short* __restrict__ Xbf)
{
    const int row = blockIdx.x;
    const int c = row & (CC - 1);
    const int t = idx[row];
    const int m0 = threadIdx.x * 2;
    float o[2];
#pragma unroll
    for (int i = 0; i < 2; ++i) {
        const int m = m0 + i;
        const double dn = pow(10000.0, (double)m * (1.0 / 511.0));
        const double arg = (double)c / dn;
        const double pv = (m & 1) ? cos(arg) : sin(arg);
        o[i] = emb[(size_t)t * MM + m] + (float)pv;
    }
    *(float2*)(X + (size_t)row * MM + m0) = make_float2(o[0], o[1]);
    const unsigned short h0 = f2bf(o[0]), h1 = f2bf(o[1]);
    const unsigned short l0 = f2bf(o[0] - bf2f(h0)), l1 = f2bf(o[1] - bf2f(h1));
    const size_t base = (size_t)row * 1024 + (size_t)(threadIdx.x >> 2) * 16 + (m0 & 7);
    *(unsigned*)&Xbf[base]     = h0 | ((unsigned)h1 << 16);
    *(unsigned*)&Xbf[base + 8] = l0 | ((unsigned)l1 << 16);
}

// ---------------------------------------------------------------------------
__global__ __launch_bounds__(256) void rowstat_ker(const float* __restrict__ Z,
                                                   float* __restrict__ stats)
{
    const int row = blockIdx.x;
    const float* z = Z + (size_t)row * TT;
    const int tid = threadIdx.x;
    float mx = -3.4e38f;
    for (int i = tid; i < TT; i += 256) mx = fmaxf(mx, z[i]);
#pragma unroll
    for (int o = 32; o; o >>= 1) mx = fmaxf(mx, __shfl_xor(mx, o, 64));
    __shared__ float red[4];
    if ((tid & 63) == 0) red[tid >> 6] = mx;
    __syncthreads();
    mx = fmaxf(fmaxf(red[0], red[1]), fmaxf(red[2], red[3]));
    float sm = 0.f;
    for (int i = tid; i < TT; i += 256) sm += expf(z[i] - mx);
#pragma unroll
    for (int o = 32; o; o >>= 1) sm += __shfl_xor(sm, o, 64);
    __syncthreads();
    if ((tid & 63) == 0) red[tid >> 6] = sm;
    __syncthreads();
    sm = red[0] + red[1] + red[2] + red[3];
    if (tid == 0) { stats[2 * row] = mx; stats[2 * row + 1] = 1.f / sm; }
}

__global__ __launch_bounds__(256) void finalnorm_ker(float* __restrict__ Z,
                                                     const float* __restrict__ stats)
{
    const unsigned i4 = blockIdx.x * 256u + threadIdx.x;
    const unsigned idx = i4 * 4u;
    const unsigned row = idx / (unsigned)TT;
    const float mx = stats[2 * row], inv = stats[2 * row + 1];
    float4 v = ((float4*)Z)[i4];
    v.x = expf(v.x - mx) * inv;
    v.y = expf(v.y - mx) * inv;
    v.z = expf(v.z - mx) * inv;
    v.w = expf(v.w - mx) * inv;
    ((float4*)Z)[i4] = v;
}

// ---------------------------------------------------------------------------
extern "C" void kernel_launch(void* const* d_in, const int* in_sizes, int n_in,
                              void* d_out, int out_size, void* d_ws, size_t ws_size,
                              hipStream_t stream)
{
    const float* enc = (const float*)d_in[0];
    const int*   dec = (const int*)d_in[1];
    const float* emb = (const float*)d_in[2];
    const float* wq  = (const float*)d_in[3];
    const float* wk  = (const float*)d_in[4];
    const float* wv  = (const float*)d_in[5];
    const float* wo  = (const float*)d_in[6];
    const float* w1  = (const float*)d_in[7];
    const float* b1  = (const float*)d_in[8];
    const float* w2  = (const float*)d_in[9];
    const float* b2  = (const float*)d_in[10];
    const float* lng = (const float*)d_in[11];
    const float* lnb = (const float*)d_in[12];
    const float* wf  = (const float*)d_in[13];
    const float* bf  = (const float*)d_in[14];
    float* out = (float*)d_out;

    // ws layout (~144 MB)
    unsigned short* Wattn = (unsigned short*)d_ws;          // 12*4*524288 u  = 48 MB
    unsigned short* Wffn  = Wattn + (size_t)25165824;       // 6*4194304 u    = 48 MB
    unsigned short* encbf = Wffn  + (size_t)25165824;       // 2M u = 4 MB
    unsigned short* xbf   = encbf + 2097152;                // 4 MB
    unsigned short* prebf = xbf   + 2097152;                // 4 MB
    unsigned short* hidbf = prebf + 2097152;                // 8M u = 16 MB
    float* xf    = (float*)(hidbf + 8388608);               // 4 MB
    float* yf    = xf + 1048576;                            // 4 MB
    float* qb    = yf + 1048576;                            // 4 MB
    float* kbuf  = qb + 1048576;                            // 4 MB
    float* vbuf  = kbuf + 1048576;                          // 4 MB
    float* stats = vbuf + 1048576;                          // 16 KB

    conv_weights<<<dim3(6144), 256, 0, stream>>>(wq, wk, wv, wo, w1, w2, Wattn, Wffn);
    conv_act<<<dim3(512), 256, 0, stream>>>(enc, encbf);
    embed_ker<<<dim3(NROWS), 256, 0, stream>>>(dec, emb, xf, xbf);

    for (int l = 0; l < LLAYERS; ++l) {
        for (int s = 0; s < 2; ++s) {
            const int l2 = l * 2 + s;
            const unsigned short* Wc = Wattn + (size_t)l2 * 2097152;
            g_qkv<<<dim3(16, 4, 3), 256, 0, stream>>>(xbf, s ? encbf : xbf, Wc,
                                                      qb, kbuf, vbuf);
            if (s == 0)
                attn_ker<true><<<dim3(32, 8, 4), 256, 0, stream>>>(qb, kbuf, vbuf, prebf);
            else
                attn_ker<false><<<dim3(32, 8, 4), 256, 0, stream>>>(qb, kbuf, vbuf, prebf);
            g_wo<<<dim3(16, 4), 256, 0, stream>>>(prebf, Wc + (size_t)3 * 524288, yf, xf);
            ln_ker<<<dim3(NROWS), 256, 0, stream>>>(yf, xf, xbf,
                lng + (size_t)(l * 3 + s) * MM, lnb + (size_t)(l * 3 + s) * MM);
        }
        g_ffn1<<<dim3(16, 16), 256, 0, stream>>>(xbf, Wffn + (size_t)l * 4194304,
                                                 hidbf, b1 + (size_t)l * FF);
        g_ffn2<<<dim3(16, 4), 256, 0, stream>>>(hidbf, Wffn + (size_t)l * 4194304 + 2097152,
                                                yf, xf, b2 + (size_t)l * MM);
        ln_ker<<<dim3(NROWS), 256, 0, stream>>>(yf, xf, xbf,
            lng + (size_t)(l * 3 + 2) * MM, lnb + (size_t)(l * 3 + 2) * MM);
    }

    g_transb<<<dim3(16, 250), 256, 0, stream>>>(xbf, wf, out, bf);
    rowstat_ker<<<dim3(NROWS), 256, 0, stream>>>(out, stats);
    finalnorm_ker<<<dim3(64000), 256, 0, stream>>>(out, stats);
}